// Round 2
// baseline (223.034 us; speedup 1.0000x reference)
//
#include <hip/hip_runtime.h>
#include <math.h>

// Side-window filter, FP32, bit-exact vs the np reference (absmax==0.0):
// each directional conv is a sequential fp32 FMA chain over taps in row-major
// (ky,kx) order, acc starting at 0, weights fp32(1/15), fp32(1/9),
// fp32(fp32(1/9)/9). Zero-padded taps are exact no-ops.
//
// Round 8: 3-dispatch path (x->out, out->ws, ws->out). The fused kernel was
// VALU-issue-bound (VALUBusy 85.2%, 112 us of issue in 131.8 us) with a 1.20x
// halo-recompute ratio. Per-iteration dispatches eliminate recompute
// (51.0M -> 42.5M pixel-iterations), drop LDS to 9.8 KB (8 blocks/CU,
// 32 waves/CU, threads-limited), remove the interior/edge select path, and
// make NSEG=512 = exactly 2 full wave passes (no tail imbalance).
// Inter-iteration traffic 56.6 MB/step is ~9 us at HBM rate and mostly
// L3-resident — far under the roofline, overlapped with compute.
// Falls back to the verified fused kernel if ws_size < one image (56.6 MB).
//
// Direction supports (with the reference's normalization bug):
//   d0 L  = rows[-2..2] x cols[-2..0] * (1/15)
//   d1 R  = rows[-2..2] x cols[0..2]  * (1/15)
//   d2 U  = rows[-2..0] x cols[-2..2] * (1/15)
//   d3 D  = rows[0..2]  x cols[-2..2] * (1/15)
//   d4 NW = rows[-2..0] x cols[-2..0] * (1/9)
//   d5 NE = NW support * (1/81)   (bug: NE = new NW / 9)
//   d6 SW = rows[0..2]  x cols[-2..0] * (1/9)
//   d7 SE = SW support * (1/81)   (bug: SE = new SW / 9)

typedef float f4v __attribute__((ext_vector_type(4)));
typedef float f2v __attribute__((ext_vector_type(2), aligned(8)));

#define TW 64
#define TH 32

// Core math for 4 horizontally-adjacent pixels. rp points at the (-2,-2) tap
// of pixel 0 in an LDS tile of pitch PW floats (rows 16B-aligned). The
// per-accumulator op order (rows ascending, cols ascending within row) is the
// verified bit-exact chain — do not reorder.
template<int PW>
__device__ __forceinline__ f4v swf4(const float* __restrict__ rp) {
    const float w15 = 1.0f / 15.0f;
    const float w9  = 1.0f / 9.0f;
    const float w81 = (1.0f / 9.0f) / 9.0f;

    float acc[8][4];
    #pragma unroll
    for (int d = 0; d < 8; d++)
        #pragma unroll
        for (int j = 0; j < 4; j++) acc[d][j] = 0.0f;
    float ctr[4];

    #pragma unroll
    for (int r = 0; r < 5; r++) {
        const float* p = rp + r * PW;     // 16B-aligned
        f4v lo = *(const f4v*)p;
        f4v hi = *(const f4v*)(p + 4);
        float w[8] = {lo.x, lo.y, lo.z, lo.w, hi.x, hi.y, hi.z, hi.w};

        #pragma unroll
        for (int j = 0; j < 4; j++) {
            // full-height: L (cols j..j+2), R (cols j+2..j+4)
            acc[0][j] = fmaf(w15, w[j + 0], acc[0][j]);
            acc[0][j] = fmaf(w15, w[j + 1], acc[0][j]);
            acc[0][j] = fmaf(w15, w[j + 2], acc[0][j]);
            acc[1][j] = fmaf(w15, w[j + 2], acc[1][j]);
            acc[1][j] = fmaf(w15, w[j + 3], acc[1][j]);
            acc[1][j] = fmaf(w15, w[j + 4], acc[1][j]);
            if (r < 3) {  // U, NW, NE
                acc[2][j] = fmaf(w15, w[j + 0], acc[2][j]);
                acc[2][j] = fmaf(w15, w[j + 1], acc[2][j]);
                acc[2][j] = fmaf(w15, w[j + 2], acc[2][j]);
                acc[2][j] = fmaf(w15, w[j + 3], acc[2][j]);
                acc[2][j] = fmaf(w15, w[j + 4], acc[2][j]);
                acc[4][j] = fmaf(w9,  w[j + 0], acc[4][j]);
                acc[4][j] = fmaf(w9,  w[j + 1], acc[4][j]);
                acc[4][j] = fmaf(w9,  w[j + 2], acc[4][j]);
                acc[5][j] = fmaf(w81, w[j + 0], acc[5][j]);
                acc[5][j] = fmaf(w81, w[j + 1], acc[5][j]);
                acc[5][j] = fmaf(w81, w[j + 2], acc[5][j]);
            }
            if (r >= 2) {  // D, SW, SE
                acc[3][j] = fmaf(w15, w[j + 0], acc[3][j]);
                acc[3][j] = fmaf(w15, w[j + 1], acc[3][j]);
                acc[3][j] = fmaf(w15, w[j + 2], acc[3][j]);
                acc[3][j] = fmaf(w15, w[j + 3], acc[3][j]);
                acc[3][j] = fmaf(w15, w[j + 4], acc[3][j]);
                acc[6][j] = fmaf(w9,  w[j + 0], acc[6][j]);
                acc[6][j] = fmaf(w9,  w[j + 1], acc[6][j]);
                acc[6][j] = fmaf(w9,  w[j + 2], acc[6][j]);
                acc[7][j] = fmaf(w81, w[j + 0], acc[7][j]);
                acc[7][j] = fmaf(w81, w[j + 1], acc[7][j]);
                acc[7][j] = fmaf(w81, w[j + 2], acc[7][j]);
            }
            if (r == 2) ctr[j] = w[j + 2];
        }
    }

    f4v R;
    #pragma unroll
    for (int j = 0; j < 4; j++) {
        const float c = ctr[j];
        const float e0 = acc[0][j] - c, e1 = acc[1][j] - c;
        const float e2 = acc[2][j] - c, e3 = acc[3][j] - c;
        const float e4 = acc[4][j] - c, e5 = acc[5][j] - c;
        const float e6 = acc[6][j] - c, e7 = acc[7][j] - c;
        // tournament argmin on |d|; strict < keeps lowest index on ties
        // (matches jnp.argmin); |x| folds into VOP3 abs modifiers
        float m01 = (fabsf(e1) < fabsf(e0)) ? e1 : e0;
        float m23 = (fabsf(e3) < fabsf(e2)) ? e3 : e2;
        float m45 = (fabsf(e5) < fabsf(e4)) ? e5 : e4;
        float m67 = (fabsf(e7) < fabsf(e6)) ? e7 : e6;
        float mA  = (fabsf(m23) < fabsf(m01)) ? m23 : m01;
        float mB  = (fabsf(m67) < fabsf(m45)) ? m67 : m45;
        float bd  = (fabsf(mB)  < fabsf(mA))  ? mB  : mA;
        const float res = c + bd;
        if (j == 0) R.x = res; else if (j == 1) R.y = res;
        else if (j == 2) R.z = res; else R.w = res;
    }
    return R;
}

// ---------------- 3-dispatch path: one SWF iteration per dispatch ----------
// Stage (TH+4)x(TW+4) = 36x68 with zero-padded +-2 halo, compute TH x TW,
// store straight to global (every output pixel is in-image). LDS 9792 B ->
// 8 blocks/CU (threads-limited), 32 waves/CU.
__global__ __launch_bounds__(256, 8) void swf_step1(const float* __restrict__ in,
                                                    float* __restrict__ out) {
    __shared__ __align__(16) float A[36 * 68];

    const int tid = threadIdx.x;
    const int tx0 = blockIdx.x * TW;
    const int ty0 = blockIdx.y * TH;
    const long long base = (long long)blockIdx.z * (768 * 768);
    const float* inp = in + base;

    // stage rows ty0-2..ty0+33, cols tx0-2..tx0+65, zero-padded.
    // float2 granularity: global col tx0-2 is even -> 8B aligned.
    for (int i = tid; i < 36 * 34; i += 256) {
        const int ly  = i / 34;
        const int lx2 = i - ly * 34;
        const int gy  = ty0 + ly - 2;
        const int gx  = tx0 + lx2 * 2 - 2;
        f2v v = {0.0f, 0.0f};
        if ((unsigned)gy < 768u) {
            const float* g = inp + gy * 768 + gx;
            if ((unsigned)gx < 767u) {            // both lanes inside
                v = *(const f2v*)g;
            } else {                               // x-edge: per-lane
                if ((unsigned)gx < 768u)       v.x = g[0];
                if ((unsigned)(gx + 1) < 768u) v.y = g[1];
            }
        }
        *(f2v*)(A + ly * 68 + lx2 * 2) = v;
    }
    __syncthreads();

    float* op = out + base + (long long)ty0 * 768 + tx0;
    // NSEG = 32*16 = 512 = exactly 2 full 256-thread passes (no tail).
    // Keep un-unrolled: one segment's 8 indep FMA chains already give ILP,
    // and unrolling would double acc[] pressure past the 64-VGPR / 8-wave cap.
    #pragma unroll 1
    for (int s = tid; s < 512; s += 256) {
        const int y  = s >> 4;
        const int xs = (s & 15) * 4;
        f4v R = swf4<68>(A + y * 68 + xs);
        *(f4v*)(op + y * 768 + xs) = R;   // 16B-aligned: tx0%64==0, xs%4==0
    }
}

// ---------------- fused fallback (ws too small) ----------------------------
// One SWF iteration. X: (H2+4) x (W2+4) fp32 LDS tile (pitch W2+4), zero-pad.
// Y: H2 x W2 (pitch W2), zeroed outside the 768x768 image (gy0,gx0 = global
// coords of Y[0][0]); if LAST, write fp32 to outp (pitch 768).
template<int H2, int W2, bool LAST>
__device__ __forceinline__ void step(const float* __restrict__ X,
                                     float* __restrict__ Y,
                                     float* __restrict__ outp,
                                     int gy0, int gx0, int tid) {
    constexpr int PW = W2 + 4;
    constexpr int SC = W2 / 4;
    constexpr int NSEG = H2 * SC;

    const bool interior = (gy0 >= 0) && (gx0 >= 0) &&
                          (gy0 + H2 <= 768) && (gx0 + W2 <= 768);

    for (int s = tid; s < NSEG; s += 256) {
        const int y  = s / SC;
        const int xs = (s - y * SC) * 4;
        f4v R = swf4<PW>(X + y * PW + xs);

        if (LAST) {
            *(f4v*)(outp + y * 768 + xs) = R;
        } else if (interior) {
            *(f4v*)(Y + y * W2 + xs) = R;
        } else {
            const bool rowin = ((unsigned)(gy0 + y) < 768u);
            R.x = (rowin && (unsigned)(gx0 + xs + 0) < 768u) ? R.x : 0.0f;
            R.y = (rowin && (unsigned)(gx0 + xs + 1) < 768u) ? R.y : 0.0f;
            R.z = (rowin && (unsigned)(gx0 + xs + 2) < 768u) ? R.z : 0.0f;
            R.w = (rowin && (unsigned)(gx0 + xs + 3) < 768u) ? R.w : 0.0f;
            *(f4v*)(Y + y * W2 + xs) = R;
        }
    }
    __syncthreads();
}

__global__ __launch_bounds__(256) void swf_fused(const float* __restrict__ in,
                                                 float* __restrict__ out) {
    __shared__ __align__(16) float A[44 * 76];
    __shared__ __align__(16) float B[40 * 72];

    const int tid = threadIdx.x;
    const int tx0 = blockIdx.x * TW;
    const int ty0 = blockIdx.y * TH;
    const long long base = (long long)blockIdx.z * (768 * 768);
    const float* inp = in + base;

    for (int i = tid; i < 44 * 38; i += 256) {
        const int ly  = i / 38;
        const int lx2 = i - ly * 38;
        const int gy  = ty0 + ly - 6;
        const int gx  = tx0 + lx2 * 2 - 6;
        f2v v = {0.0f, 0.0f};
        if ((unsigned)gy < 768u) {
            const float* g = inp + gy * 768 + gx;
            if ((unsigned)gx < 767u) {
                v = *(const f2v*)g;
            } else {
                if ((unsigned)gx < 768u)       v.x = g[0];
                if ((unsigned)(gx + 1) < 768u) v.y = g[1];
            }
        }
        *(f2v*)(A + ly * 76 + lx2 * 2) = v;
    }
    __syncthreads();

    step<40, 72, false>(A, B, nullptr, ty0 - 4, tx0 - 4, tid);  // iter1: A->B
    step<36, 68, false>(B, A, nullptr, ty0 - 2, tx0 - 2, tid);  // iter2: B->A
    step<32, 64, true >(A, nullptr,                              // iter3: A->out
                        out + base + (long long)ty0 * 768 + tx0, ty0, tx0, tid);
}

extern "C" void kernel_launch(void* const* d_in, const int* in_sizes, int n_in,
                              void* d_out, int out_size, void* d_ws, size_t ws_size,
                              hipStream_t stream) {
    const float* x = (const float*)d_in[0];
    float* out = (float*)d_out;

    const size_t IMG_BYTES = (size_t)768 * 768 * 24 * sizeof(float); // 56.6 MB
    dim3 grid(768 / TW, 768 / TH, 24);   // 12 x 24 x 24 = 6912 blocks
    dim3 block(256);

    if (ws_size >= IMG_BYTES && d_ws != nullptr) {
        float* ws = (float*)d_ws;
        // iter1: x -> out, iter2: out -> ws, iter3: ws -> out.
        // Stream ordering makes each dispatch's writes visible to the next.
        swf_step1<<<grid, block, 0, stream>>>(x, out);
        swf_step1<<<grid, block, 0, stream>>>(out, ws);
        swf_step1<<<grid, block, 0, stream>>>(ws, out);
    } else {
        swf_fused<<<grid, block, 0, stream>>>(x, out);
    }
}